// Round 1
// 921.556 us; speedup vs baseline: 1.0419x; 1.0419x over previous
//
#include <hip/hip_runtime.h>
#include <cfloat>
#include <math.h>

#define N_NODES 500000
#define C_DIM   256
#define R_DIM   64
#define G_NUM   4096

// native clang vector type so __builtin_nontemporal_{load,store} accept it
typedef float f32x4 __attribute__((ext_vector_type(4)));

// ---------------------------------------------------------------------------
// Fully fused kernel. One block (256 thr) per graph g:
//   phase 1: segment max+sum pool over rows [start,end)   (streams x from HBM)
//   phase 2: y = sigmoid(W2*(relu(W1*zmax)+relu(W1*zsum)))  (weights L2-hot)
//   phase 3: out[n] = x[n] * y  for n in [start,end)      (x re-read is L2/L3
//            warm -- the block just streamed those exact 122 KB)
// out is written non-temporally so it doesn't evict the x window from L3.
// No workspace, no inter-kernel HBM round trips, one dispatch.
// ---------------------------------------------------------------------------
__global__ __launch_bounds__(256) void fused_kernel(
    const float* __restrict__ x, const int* __restrict__ batch,
    const float* __restrict__ w1, const float* __restrict__ w2,
    float* __restrict__ out) {
  const int g = blockIdx.x;

  // lower_bound(batch, g) / lower_bound(batch, g+1); all lanes same address ->
  // wave-broadcast loads, batch (2 MB) is L2/L3 resident.
  int lo = 0, hi = N_NODES;
  while (lo < hi) { int mid = (lo + hi) >> 1; if (batch[mid] < g) lo = mid + 1; else hi = mid; }
  const int start = lo;
  hi = N_NODES;
  while (lo < hi) { int mid = (lo + hi) >> 1; if (batch[mid] <= g) lo = mid + 1; else hi = mid; }
  const int end = lo;
  if (end == start) return;  // empty graph: contributes no output rows

  const int tid = threadIdx.x;
  const int c4  = tid & 63;   // which float4 of the 256-channel row
  const int rg  = tid >> 6;   // row-group 0..3 (one wave each)

  __shared__ f32x4 smax[4][64];   // 4 KB
  __shared__ f32x4 ssum[4][64];   // 4 KB
  __shared__ float zm[C_DIM];     // 1 KB
  __shared__ float zs[C_DIM];     // 1 KB
  __shared__ float red_m[256];    // 1 KB
  __shared__ float red_s[256];    // 1 KB
  __shared__ float hs[R_DIM];     // 256 B
  __shared__ float yl[C_DIM];     // 1 KB   (~13.3 KB total -> 8 blocks/CU)

  // ---- phase 1: pool ------------------------------------------------------
  f32x4 vmax = { -FLT_MAX, -FLT_MAX, -FLT_MAX, -FLT_MAX };
  f32x4 vsum = { 0.f, 0.f, 0.f, 0.f };
  const f32x4* __restrict__ xr = (const f32x4*)x;
  for (int n = start + rg; n < end; n += 4) {
    f32x4 v = xr[(size_t)n * 64 + c4];   // caching load: we re-read in phase 3
    vmax.x = fmaxf(vmax.x, v.x); vmax.y = fmaxf(vmax.y, v.y);
    vmax.z = fmaxf(vmax.z, v.z); vmax.w = fmaxf(vmax.w, v.w);
    vsum += v;
  }
  smax[rg][c4] = vmax;
  ssum[rg][c4] = vsum;
  __syncthreads();

  if (rg == 0) {
    for (int i = 1; i < 4; ++i) {
      f32x4 m = smax[i][c4];
      vmax.x = fmaxf(vmax.x, m.x); vmax.y = fmaxf(vmax.y, m.y);
      vmax.z = fmaxf(vmax.z, m.z); vmax.w = fmaxf(vmax.w, m.w);
      vsum += ssum[i][c4];
    }
    // segment is non-empty here, so no neginf fixup needed
    ((f32x4*)zm)[c4] = vmax;
    ((f32x4*)zs)[c4] = vsum;
  }
  __syncthreads();

  // ---- phase 2a: layer 1  h[r] = relu(w1[r].zm) + relu(w1[r].zs) ---------
  {
    const int r    = tid & 63;
    const int part = tid >> 6;
    float pm = 0.f, ps = 0.f;
    const float* w1r = w1 + (size_t)r * C_DIM + part * 64;
    const float* zmp = zm + part * 64;
    const float* zsp = zs + part * 64;
#pragma unroll 8
    for (int c = 0; c < 64; ++c) {
      float w = w1r[c];
      pm += w * zmp[c];   // same LDS address across the wave -> broadcast
      ps += w * zsp[c];
    }
    red_m[tid] = pm;
    red_s[tid] = ps;
    __syncthreads();
    if (part == 0) {
      float am = pm + red_m[64 + r] + red_m[128 + r] + red_m[192 + r];
      float as = ps + red_s[64 + r] + red_s[128 + r] + red_s[192 + r];
      hs[r] = fmaxf(am, 0.f) + fmaxf(as, 0.f);
    }
    __syncthreads();
  }

  // ---- phase 2b: layer 2 + sigmoid; thread tid owns channel tid ----------
  {
    float acc = 0.f;
    const f32x4* w2c = (const f32x4*)(w2 + (size_t)tid * R_DIM);
#pragma unroll
    for (int q = 0; q < R_DIM / 4; ++q) {
      f32x4 w = w2c[q];
      acc += w.x * hs[4 * q + 0] + w.y * hs[4 * q + 1] +
             w.z * hs[4 * q + 2] + w.w * hs[4 * q + 3];
    }
    yl[tid] = 1.f / (1.f + expf(-acc));
  }
  __syncthreads();

  // ---- phase 3: apply  out[n] = x[n] * y ---------------------------------
  {
    const f32x4 y4 = ((const f32x4*)yl)[c4];
    f32x4* outr = (f32x4*)out;
    for (int n = start + rg; n < end; n += 4) {
      f32x4 v = __builtin_nontemporal_load(&xr[(size_t)n * 64 + c4]);
      v *= y4;
      __builtin_nontemporal_store(v, &outr[(size_t)n * 64 + c4]);
    }
  }
}

extern "C" void kernel_launch(void* const* d_in, const int* in_sizes, int n_in,
                              void* d_out, int out_size, void* d_ws, size_t ws_size,
                              hipStream_t stream) {
  const float* x     = (const float*)d_in[0];
  const int*   batch = (const int*)d_in[1];
  const float* w1    = (const float*)d_in[2];
  const float* w2    = (const float*)d_in[3];
  float* out = (float*)d_out;
  (void)d_ws; (void)ws_size;

  fused_kernel<<<G_NUM, 256, 0, stream>>>(x, batch, w1, w2, out);
}